// Round 10
// baseline (1574.402 us; speedup 1.0000x reference)
//
#include <hip/hip_runtime.h>

#define NN 100000
#define NE 1600000
constexpr float BN_EPS = 1e-5f;
constexpr float LRELU_SLOPE = 0.01f;
constexpr int SC_NB = (NN + 255) / 256;  // 391 scan blocks
constexpr int RSH = 13;                  // range shift (8192)
constexpr int RB = 1 << RSH;             // 8192 nodes per range-bucket
constexpr int NR = (NN + RB - 1) / RB;   // 13 buckets
constexpr int SB = 8;                    // slices per bucket (phase 2/4)
constexpr int CAP = 163840;              // bucket capacity
constexpr int PBLK = 400;                // partition blocks
constexpr int PCHUNK = NE / PBLK;        // 4000 edges per partition block

// ---------------------------------------------------------------- P1: partition edges by col-range / row-range
__global__ __launch_bounds__(256) void k_part(const int* __restrict__ row,
                                              const int* __restrict__ col,
                                              int* __restrict__ colCnt,
                                              int* __restrict__ rowCnt,
                                              int* __restrict__ colbuf,
                                              unsigned short* __restrict__ rowbuf) {
  __shared__ int cntc[NR], cntr[NR];
  const int tid = threadIdx.x;
  const int e0 = blockIdx.x * PCHUNK;
  if (tid < NR) { cntc[tid] = 0; cntr[tid] = 0; }
  __syncthreads();
  for (int i = tid; i < PCHUNK; i += 256) {
    atomicAdd(&cntc[col[e0 + i] >> RSH], 1);
    atomicAdd(&cntr[row[e0 + i] >> RSH], 1);
  }
  __syncthreads();
  if (tid < NR) {
    cntc[tid] = atomicAdd(&colCnt[tid], cntc[tid]);
  } else if (tid >= 64 && tid < 64 + NR) {
    const int b = tid - 64;
    cntr[b] = atomicAdd(&rowCnt[b], cntr[b]);
  }
  __syncthreads();
  for (int i = tid; i < PCHUNK; i += 256) {
    const int r = row[e0 + i];
    const int c = col[e0 + i];
    const int bc = c >> RSH;
    const int pc = atomicAdd(&cntc[bc], 1);
    colbuf[(size_t)bc * CAP + pc] = (r << RSH) | (c & (RB - 1));
    const int br = r >> RSH;
    const int pr = atomicAdd(&cntr[br], 1);
    rowbuf[(size_t)br * CAP + pr] = (unsigned short)(r & (RB - 1));
  }
}

// ---------------------------------------------------------------- P2: per-(bucket,slice) LDS histogram
__global__ __launch_bounds__(1024) void k_hist2(const int* __restrict__ colbuf,
                                                const unsigned short* __restrict__ rowbuf,
                                                const int* __restrict__ colCnt,
                                                const int* __restrict__ rowCnt,
                                                int* __restrict__ PDc,
                                                int* __restrict__ PDd) {
  __shared__ int h[RB];
  const int tid = threadIdx.x;
  const int b = blockIdx.x, s = blockIdx.y, z = blockIdx.z;
  for (int i = tid; i < RB; i += 1024) h[i] = 0;
  __syncthreads();
  const int len = z ? rowCnt[b] : colCnt[b];
  const int sl = (len + SB - 1) / SB;
  const int st = s * sl;
  const int en = min(st + sl, len);
  if (z == 0) {
    const int* cb = colbuf + (size_t)b * CAP;
    for (int i = st + tid; i < en; i += 1024)
      atomicAdd(&h[cb[i] & (RB - 1)], 1);
  } else {
    const unsigned short* rb = rowbuf + (size_t)b * CAP;
    for (int i = st + tid; i < en; i += 1024)
      atomicAdd(&h[rb[i]], 1);
  }
  __syncthreads();
  int* pd = (z ? PDd : PDc) + ((size_t)b * SB + s) * RB;
  for (int i = tid; i < RB; i += 1024) pd[i] = h[i];
}

// ---------------------------------------------------------------- P3: per-node slice prefix + totals + dinv
__global__ __launch_bounds__(256) void k_csrmid2(const int* __restrict__ PDc,
                                                 const int* __restrict__ PDd,
                                                 int* __restrict__ Bpart,
                                                 int* __restrict__ cnt,
                                                 float* __restrict__ dinv) {
  const int n = blockIdx.x * 256 + threadIdx.x;
  if (n >= NN) return;
  const int b = n >> RSH, o = n & (RB - 1);
  int run = 0, dsum = 0;
#pragma unroll
  for (int s = 0; s < SB; s++) {
    Bpart[(size_t)s * NN + n] = run;
    run += PDc[((size_t)b * SB + s) * RB + o];
    dsum += PDd[((size_t)b * SB + s) * RB + o];
  }
  cnt[n] = run;
  dinv[n] = dsum > 0 ? rsqrtf((float)dsum) : 0.0f;
}

// ---------------------------------------------------------------- 3-phase exclusive scan of cnt
__global__ __launch_bounds__(256) void k_scan_a(const int* __restrict__ cnt,
                                                int* __restrict__ bsum) {
  __shared__ int sh[256];
  const int tid = threadIdx.x;
  const int i = blockIdx.x * 256 + tid;
  sh[tid] = (i < NN) ? cnt[i] : 0;
  __syncthreads();
  for (int st = 128; st > 0; st >>= 1) {
    if (tid < st) sh[tid] += sh[tid + st];
    __syncthreads();
  }
  if (tid == 0) bsum[blockIdx.x] = sh[0];
}

__global__ __launch_bounds__(512) void k_scan_b(const int* __restrict__ bsum,
                                                int* __restrict__ boff) {
  __shared__ int sh[512];
  const int tid = threadIdx.x;
  const int v = (tid < SC_NB) ? bsum[tid] : 0;
  sh[tid] = v;
  __syncthreads();
  for (int off = 1; off < 512; off <<= 1) {
    int t = (tid >= off) ? sh[tid - off] : 0;
    __syncthreads();
    sh[tid] += t;
    __syncthreads();
  }
  if (tid < SC_NB) boff[tid] = sh[tid] - v;  // exclusive
}

__global__ __launch_bounds__(256) void k_scan_c(const int* __restrict__ cnt,
                                                const int* __restrict__ boff,
                                                int* __restrict__ ptr) {
  __shared__ int sh[256];
  const int tid = threadIdx.x;
  const int i = blockIdx.x * 256 + tid;
  const int v = (i < NN) ? cnt[i] : 0;
  sh[tid] = v;
  __syncthreads();
  for (int off = 1; off < 256; off <<= 1) {
    int t = (tid >= off) ? sh[tid - off] : 0;
    __syncthreads();
    sh[tid] += t;
    __syncthreads();
  }
  const int excl = sh[tid] - v + boff[blockIdx.x];
  if (i < NN) {
    ptr[i] = excl;
    if (i == NN - 1) ptr[NN] = excl + v;
  }
}

// ---------------------------------------------------------------- P4: place edges via LDS cursors
__global__ __launch_bounds__(1024) void k_fill4(const int* __restrict__ colbuf,
                                                const int* __restrict__ colCnt,
                                                const int* __restrict__ ptr,
                                                const int* __restrict__ Bpart,
                                                int* __restrict__ eb) {
  __shared__ int cur[RB];
  const int tid = threadIdx.x;
  const int b = blockIdx.x, s = blockIdx.y;
  const int base = b << RSH;
  const int nmax = min(RB, NN - base);
  const int* bp = Bpart + (size_t)s * NN + base;
  for (int i = tid; i < nmax; i += 1024) cur[i] = ptr[base + i] + bp[i];
  __syncthreads();
  const int len = colCnt[b];
  const int sl = (len + SB - 1) / SB;
  const int st = s * sl;
  const int en = min(st + sl, len);
  const int* cb = colbuf + (size_t)b * CAP;
  for (int i = st + tid; i < en; i += 1024) {
    const int rec = cb[i];
    const int pos = atomicAdd(&cur[rec & (RB - 1)], 1);
    eb[pos] = rec >> RSH;
  }
}

// ---------------------------------------------------------------- prop: acc[n] = sum_{e: col=n} [dinv[s]*] p[src_e]
template <bool SCALE, bool ADD>
__global__ __launch_bounds__(256) void k_prop64(const float* __restrict__ p,
                                                const int* __restrict__ eb,
                                                const int* __restrict__ ptr,
                                                const float* __restrict__ g,
                                                const float* __restrict__ dinv,
                                                float* __restrict__ out) {
  const int node = blockIdx.x * 16 + (threadIdx.x >> 4);
  const int lane = threadIdx.x & 15;
  if (node >= NN) return;
  const int b = ptr[node], e = ptr[node + 1];
  float4 a0 = make_float4(0.f, 0.f, 0.f, 0.f);
  float4 a1 = make_float4(0.f, 0.f, 0.f, 0.f);
  float4 a2 = make_float4(0.f, 0.f, 0.f, 0.f);
  float4 a3 = make_float4(0.f, 0.f, 0.f, 0.f);
  const float4* hp = reinterpret_cast<const float4*>(p) + lane;
  int j = b;
  for (; j + 4 <= e; j += 4) {
    const int s0 = eb[j], s1 = eb[j + 1], s2 = eb[j + 2], s3 = eb[j + 3];
    const float w0 = SCALE ? dinv[s0] : 1.f;
    const float w1 = SCALE ? dinv[s1] : 1.f;
    const float w2 = SCALE ? dinv[s2] : 1.f;
    const float w3 = SCALE ? dinv[s3] : 1.f;
    const float4 h0 = hp[(size_t)s0 * 16];
    const float4 h1 = hp[(size_t)s1 * 16];
    const float4 h2 = hp[(size_t)s2 * 16];
    const float4 h3 = hp[(size_t)s3 * 16];
    if (SCALE) {
      a0.x += w0 * h0.x; a0.y += w0 * h0.y; a0.z += w0 * h0.z; a0.w += w0 * h0.w;
      a1.x += w1 * h1.x; a1.y += w1 * h1.y; a1.z += w1 * h1.z; a1.w += w1 * h1.w;
      a2.x += w2 * h2.x; a2.y += w2 * h2.y; a2.z += w2 * h2.z; a2.w += w2 * h2.w;
      a3.x += w3 * h3.x; a3.y += w3 * h3.y; a3.z += w3 * h3.z; a3.w += w3 * h3.w;
    } else {
      a0.x += h0.x; a0.y += h0.y; a0.z += h0.z; a0.w += h0.w;
      a1.x += h1.x; a1.y += h1.y; a1.z += h1.z; a1.w += h1.w;
      a2.x += h2.x; a2.y += h2.y; a2.z += h2.z; a2.w += h2.w;
      a3.x += h3.x; a3.y += h3.y; a3.z += h3.z; a3.w += h3.w;
    }
  }
  for (; j < e; j++) {
    const int s0 = eb[j];
    const float w0 = SCALE ? dinv[s0] : 1.f;
    const float4 h0 = hp[(size_t)s0 * 16];
    if (SCALE) {
      a0.x += w0 * h0.x; a0.y += w0 * h0.y; a0.z += w0 * h0.z; a0.w += w0 * h0.w;
    } else {
      a0.x += h0.x; a0.y += h0.y; a0.z += h0.z; a0.w += h0.w;
    }
  }
  a0.x += a1.x + a2.x + a3.x;
  a0.y += a1.y + a2.y + a3.y;
  a0.z += a1.z + a2.z + a3.z;
  a0.w += a1.w + a2.w + a3.w;
  if (ADD) {
    const float dn = dinv[node];
    const float4 gv = reinterpret_cast<const float4*>(g)[(size_t)node * 16 + lane];
    a0.x = gv.x - dn * a0.x;
    a0.y = gv.y - dn * a0.y;
    a0.z = gv.z - dn * a0.z;
    a0.w = gv.w - dn * a0.w;
  }
  reinterpret_cast<float4*>(out)[(size_t)node * 16 + lane] = a0;
}

// ---------------------------------------------------------------- layer-1 conv: h1 = x@W0 + (-dinv*y)@W1 + b
// XA/XY row copied LDS->registers in 8-k chunks (double-buffered, fully unrolled) so the
// FMA stream's lgkm domain contains ONLY s_loads of W (no ds_read drains W prefetch).
__global__ __launch_bounds__(512) void k_conv1(const float* __restrict__ x,
                                               const float* __restrict__ y,
                                               const float* __restrict__ dinv,
                                               const float* __restrict__ W,
                                               const float* __restrict__ bias,
                                               float* __restrict__ out) {
  constexpr int LDW = 68;
  __shared__ float XA[64][LDW];
  __shared__ float XY[64][LDW];
  const int tid = threadIdx.x;
  const int lane = tid & 63;
  const int wv = __builtin_amdgcn_readfirstlane(tid >> 6);  // 0..7
  const int n0 = blockIdx.x * 64;
  for (int idx = tid; idx < 1024; idx += 512) {
    const int n = idx >> 4, k4 = idx & 15;
    int node = n0 + n;
    if (node >= NN) node = NN - 1;
    const float4 av = *reinterpret_cast<const float4*>(x + (size_t)node * 64 + k4 * 4);
    float4 yv = *reinterpret_cast<const float4*>(y + (size_t)node * 64 + k4 * 4);
    const float dn = -dinv[node];
    yv.x *= dn; yv.y *= dn; yv.z *= dn; yv.w *= dn;
    *reinterpret_cast<float4*>(&XA[n][k4 * 4]) = av;
    *reinterpret_cast<float4*>(&XY[n][k4 * 4]) = yv;
  }
  __syncthreads();
  const int cw0 = wv * 16;
  const float* __restrict__ W0 = W + cw0;             // [64][128]
  const float* __restrict__ W1 = W + 64 * 128 + cw0;
  const float4* xrow = reinterpret_cast<const float4*>(&XA[lane][0]);
  const float4* yrow = reinterpret_cast<const float4*>(&XY[lane][0]);
  float acc[16];
#pragma unroll
  for (int j = 0; j < 16; j++) acc[j] = 0.f;
  float4 ca[2][2], cy[2][2];
#pragma unroll
  for (int q = 0; q < 2; q++) { ca[0][q] = xrow[q]; cy[0][q] = yrow[q]; }
#pragma unroll
  for (int cc = 0; cc < 8; cc++) {                    // chunks of 8 k
    const int cur = cc & 1, nxt = cur ^ 1;
    if (cc + 1 < 8) {
#pragma unroll
      for (int q = 0; q < 2; q++) {
        ca[nxt][q] = xrow[(cc + 1) * 2 + q];
        cy[nxt][q] = yrow[(cc + 1) * 2 + q];
      }
    }
#pragma unroll
    for (int q = 0; q < 2; q++) {
      const float4 a4 = ca[cur][q];
      const float4 y4 = cy[cur][q];
      const int k0 = cc * 8 + q * 4;
      const float ae[4] = {a4.x, a4.y, a4.z, a4.w};
      const float ye[4] = {y4.x, y4.y, y4.z, y4.w};
#pragma unroll
      for (int e = 0; e < 4; e++) {
        const int k = k0 + e;
#pragma unroll
        for (int j = 0; j < 16; j++)
          acc[j] += ae[e] * W0[(size_t)k * 128 + j] + ye[e] * W1[(size_t)k * 128 + j];
      }
    }
  }
  const int node = n0 + lane;
  if (node < NN) {
#pragma unroll
    for (int j = 0; j < 16; j += 4) {
      float4 o = make_float4(acc[j] + bias[cw0 + j], acc[j + 1] + bias[cw0 + j + 1],
                             acc[j + 2] + bias[cw0 + j + 2], acc[j + 3] + bias[cw0 + j + 3]);
      *reinterpret_cast<float4*>(out + (size_t)node * 128 + cw0 + j) = o;
    }
  }
}

// ---------------------------------------------------------------- dual GEMM: g = bn(h)@Wa + b, p = dinv * (bn(h)@Wb)
// XA row copied LDS->registers in 16-k chunks (double-buffered, fully unrolled).
template <int Cin>
__global__ __launch_bounds__(512) void k_gemm_dual(const float* __restrict__ h,
                                                   const float* __restrict__ W,
                                                   const float* __restrict__ bias,
                                                   const float* __restrict__ scale,
                                                   const float* __restrict__ shift,
                                                   const float* __restrict__ dinv,
                                                   float* __restrict__ g,
                                                   float* __restrict__ p) {
  constexpr int LDW = Cin + 4;
  __shared__ float XA[64][LDW];
  const int tid = threadIdx.x;
  const int lane = tid & 63;
  const int wv = __builtin_amdgcn_readfirstlane(tid >> 6);  // 0..7
  const int n0 = blockIdx.x * 64;
  constexpr int C4 = Cin / 4;
  for (int idx = tid; idx < 64 * C4; idx += 512) {
    const int n = idx / C4, k4 = idx % C4;
    int node = n0 + n;
    if (node >= NN) node = NN - 1;
    float4 v = *reinterpret_cast<const float4*>(h + (size_t)node * Cin + k4 * 4);
    const float4 sc = *reinterpret_cast<const float4*>(scale + k4 * 4);
    const float4 sh = *reinterpret_cast<const float4*>(shift + k4 * 4);
    v.x = sc.x * v.x + sh.x; v.y = sc.y * v.y + sh.y;
    v.z = sc.z * v.z + sh.z; v.w = sc.w * v.w + sh.w;
    v.x = v.x >= 0.f ? v.x : LRELU_SLOPE * v.x;
    v.y = v.y >= 0.f ? v.y : LRELU_SLOPE * v.y;
    v.z = v.z >= 0.f ? v.z : LRELU_SLOPE * v.z;
    v.w = v.w >= 0.f ? v.w : LRELU_SLOPE * v.w;
    *reinterpret_cast<float4*>(&XA[n][k4 * 4]) = v;
  }
  __syncthreads();
  const int cw0 = wv * 8;
  const float* __restrict__ Wa = W + cw0;              // [Cin][64]
  const float* __restrict__ Wb = W + Cin * 64 + cw0;
  const float4* xrow = reinterpret_cast<const float4*>(&XA[lane][0]);
  float ag[8], ap[8];
#pragma unroll
  for (int j = 0; j < 8; j++) { ag[j] = 0.f; ap[j] = 0.f; }
  constexpr int NCH = Cin / 16;                        // chunks of 16 k (4 float4)
  float4 cb[2][4];
#pragma unroll
  for (int q = 0; q < 4; q++) cb[0][q] = xrow[q];
#pragma unroll
  for (int cc = 0; cc < NCH; cc++) {
    const int cur = cc & 1, nxt = cur ^ 1;
    if (cc + 1 < NCH) {
#pragma unroll
      for (int q = 0; q < 4; q++) cb[nxt][q] = xrow[(cc + 1) * 4 + q];
    }
#pragma unroll
    for (int q = 0; q < 4; q++) {
      const float4 a4 = cb[cur][q];
      const int k0 = cc * 16 + q * 4;
      const float ae[4] = {a4.x, a4.y, a4.z, a4.w};
#pragma unroll
      for (int e = 0; e < 4; e++) {
        const int k = k0 + e;
#pragma unroll
        for (int j = 0; j < 8; j++) {
          ag[j] += ae[e] * Wa[(size_t)k * 64 + j];
          ap[j] += ae[e] * Wb[(size_t)k * 64 + j];
        }
      }
    }
  }
  const int node = n0 + lane;
  if (node < NN) {
    const float dn = dinv[node];
#pragma unroll
    for (int j = 0; j < 8; j += 4) {
      float4 og = make_float4(ag[j] + bias[cw0 + j], ag[j + 1] + bias[cw0 + j + 1],
                              ag[j + 2] + bias[cw0 + j + 2], ag[j + 3] + bias[cw0 + j + 3]);
      *reinterpret_cast<float4*>(g + (size_t)node * 64 + cw0 + j) = og;
      float4 op = make_float4(ap[j] * dn, ap[j + 1] * dn, ap[j + 2] * dn, ap[j + 3] * dn);
      *reinterpret_cast<float4*>(p + (size_t)node * 64 + cw0 + j) = op;
    }
  }
}

// ---------------------------------------------------------------- BN stats (per-channel sum / sumsq)
template <int C>
__global__ __launch_bounds__(256) void k_bnstats(const float* __restrict__ h,
                                                 float* __restrict__ bnsum,
                                                 float* __restrict__ bnsq) {
  constexpr int RPB = 256 / C;
  constexpr int ROWS = 256;
  const int c = threadIdx.x % C;
  const int g = threadIdx.x / C;
  const int r0 = blockIdx.x * ROWS + g;
  const int rend = min(blockIdx.x * ROWS + ROWS, NN);
  float s = 0.f, sq = 0.f;
  for (int r = r0; r < rend; r += RPB) {
    float v = h[(size_t)r * C + c];
    s += v;
    sq += v * v;
  }
  __shared__ float ss[256], sg[256];
  ss[threadIdx.x] = s;
  sg[threadIdx.x] = sq;
  __syncthreads();
  for (int st = 128; st >= C; st >>= 1) {
    if (threadIdx.x < st) {
      ss[threadIdx.x] += ss[threadIdx.x + st];
      sg[threadIdx.x] += sg[threadIdx.x + st];
    }
    __syncthreads();
  }
  if (threadIdx.x < C) {
    atomicAdd(&bnsum[threadIdx.x], ss[threadIdx.x]);
    atomicAdd(&bnsq[threadIdx.x], sg[threadIdx.x]);
  }
}

template <int C>
__global__ void k_bnfin(const float* __restrict__ bnsum, const float* __restrict__ bnsq,
                        const float* __restrict__ gamma, const float* __restrict__ beta,
                        float* __restrict__ scale, float* __restrict__ shift) {
  int c = threadIdx.x;
  if (c < C) {
    float mean = bnsum[c] * (1.0f / NN);
    float var = bnsq[c] * (1.0f / NN) - mean * mean;
    float sc = gamma[c] * rsqrtf(var + BN_EPS);
    scale[c] = sc;
    shift[c] = beta[c] - mean * sc;
  }
}

// ----------------------------------------------------------------
extern "C" void kernel_launch(void* const* d_in, const int* in_sizes, int n_in,
                              void* d_out, int out_size, void* d_ws, size_t ws_size,
                              hipStream_t stream) {
  const float* x   = (const float*)d_in[0];
  const int*   ei  = (const int*)d_in[1];
  const int*   row = ei;
  const int*   col = ei + NE;
  const float* W1  = (const float*)d_in[2];
  const float* b1  = (const float*)d_in[3];
  const float* W2  = (const float*)d_in[4];
  const float* b2  = (const float*)d_in[5];
  const float* W3  = (const float*)d_in[6];
  const float* b3  = (const float*)d_in[7];
  const float* g1  = (const float*)d_in[8];
  const float* be1 = (const float*)d_in[9];
  const float* g2w = (const float*)d_in[10];
  const float* be2 = (const float*)d_in[11];
  float* out = (float*)d_out;

  char* ws = (char*)d_ws;
  size_t off = 0;
  auto alloc = [&](size_t bytes) -> void* {
    void* p = ws + off;
    off = (off + bytes + 255) & ~(size_t)255;
    return p;
  };

  // --- zeroed region (one tiny memset) ---
  float* bnsum1 = (float*)alloc(128 * 4);
  float* bnsq1  = (float*)alloc(128 * 4);
  float* bnsum2 = (float*)alloc(64 * 4);
  float* bnsq2  = (float*)alloc(64 * 4);
  int*   colCnt = (int*)alloc(NR * 4);
  int*   rowCnt = (int*)alloc(NR * 4);
  const size_t zero_bytes = off;
  // --- rest ---
  float* dinv   = (float*)alloc(NN * 4);
  int*   cnt    = (int*)alloc(NN * 4);
  int*   ptr    = (int*)alloc((NN + 1) * 4);
  int*   bsum   = (int*)alloc(SC_NB * 4);
  int*   boff   = (int*)alloc(SC_NB * 4);
  int*   eb     = (int*)alloc((size_t)NE * 4);
  float* scale1 = (float*)alloc(128 * 4);
  float* shift1 = (float*)alloc(128 * 4);
  float* scale2 = (float*)alloc(64 * 4);
  float* shift2 = (float*)alloc(64 * 4);
  float* bufA   = (float*)alloc((size_t)NN * 64 * 4);   // y1, later g2
  float* bufB   = (float*)alloc((size_t)NN * 128 * 4);  // colbuf|rowbuf, then h1, later g3|p3
  float* bufC   = (float*)alloc((size_t)NN * 64 * 4);   // PDc|PDd|Bpart, later p2
  float* bufD   = (float*)alloc((size_t)NN * 64 * 4);   // h2

  // build scratch aliases
  int* colbuf = (int*)bufB;                                   // [NR][CAP] 4B
  unsigned short* rowbuf = (unsigned short*)(colbuf + (size_t)NR * CAP);  // [NR][CAP] 2B
  int* PDc    = (int*)bufC;                                   // [NR][SB][RB]
  int* PDd    = PDc + (size_t)NR * SB * RB;                   // [NR][SB][RB]
  int* Bpart  = PDd + (size_t)NR * SB * RB;                   // [SB][NN]

  float* y1  = bufA;
  float* h1  = bufB;
  float* gg2 = bufA;
  float* p2  = bufC;
  float* h2  = bufD;
  float* gg3 = bufB;
  float* p3  = bufB + (size_t)NN * 64;

  hipMemsetAsync(d_ws, 0, zero_bytes, stream);

  // graph prep: two-level bucket counting sort (LDS atomics only on hot path)
  k_part<<<PBLK, 256, 0, stream>>>(row, col, colCnt, rowCnt, colbuf, rowbuf);
  k_hist2<<<dim3(NR, SB, 2), 1024, 0, stream>>>(colbuf, rowbuf, colCnt, rowCnt, PDc, PDd);
  k_csrmid2<<<(NN + 255) / 256, 256, 0, stream>>>(PDc, PDd, Bpart, cnt, dinv);
  k_scan_a<<<SC_NB, 256, 0, stream>>>(cnt, bsum);
  k_scan_b<<<1, 512, 0, stream>>>(bsum, boff);
  k_scan_c<<<SC_NB, 256, 0, stream>>>(cnt, boff, ptr);
  k_fill4<<<dim3(NR, SB), 1024, 0, stream>>>(colbuf, colCnt, ptr, Bpart, eb);

  const int gemmGrid = (NN + 63) / 64;
  const int propGrid = (NN * 16 + 255) / 256;

  // layer 1: y1 = sum dinv[s]*x[s] (scale fused); h1 = x@W1[0] + (-dinv*y1)@W1[1] + b1
  k_prop64<true, false><<<propGrid, 256, 0, stream>>>(x, eb, ptr, nullptr, dinv, y1);
  k_conv1<<<gemmGrid, 512, 0, stream>>>(x, y1, dinv, W1, b1, h1);
  k_bnstats<128><<<(NN + 255) / 256, 256, 0, stream>>>(h1, bnsum1, bnsq1);
  k_bnfin<128><<<1, 128, 0, stream>>>(bnsum1, bnsq1, g1, be1, scale1, shift1);

  // layer 2: g2 = bn(h1)@W2[0]+b2, p2 = dinv*(bn(h1)@W2[1]); h2 = g2 - dinv*sum_gather(p2)
  k_gemm_dual<128><<<gemmGrid, 512, 0, stream>>>(h1, W2, b2, scale1, shift1, dinv, gg2, p2);
  k_prop64<false, true><<<propGrid, 256, 0, stream>>>(p2, eb, ptr, gg2, dinv, h2);
  k_bnstats<64><<<(NN + 255) / 256, 256, 0, stream>>>(h2, bnsum2, bnsq2);
  k_bnfin<64><<<1, 64, 0, stream>>>(bnsum2, bnsq2, g2w, be2, scale2, shift2);

  // layer 3: g3 = bn(h2)@W3[0]+b3, p3 = dinv*(bn(h2)@W3[1]); out = g3 - dinv*sum_gather(p3)
  k_gemm_dual<64><<<gemmGrid, 512, 0, stream>>>(h2, W3, b3, scale2, shift2, dinv, gg3, p3);
  k_prop64<false, true><<<propGrid, 256, 0, stream>>>(p3, eb, ptr, gg3, dinv, out);
}

// Round 12
// 836.518 us; speedup vs baseline: 1.8821x; 1.8821x over previous
//
#include <hip/hip_runtime.h>

#define NN 100000
#define NE 1600000
constexpr float BN_EPS = 1e-5f;
constexpr float LRELU_SLOPE = 0.01f;
constexpr int SC_NB = (NN + 255) / 256;  // 391 scan blocks
constexpr int RSH = 13;                  // range shift (8192)
constexpr int RB = 1 << RSH;             // 8192 nodes per range-bucket
constexpr int NR = (NN + RB - 1) / RB;   // 13 buckets
constexpr int SB = 8;                    // slices per bucket (phase 2/4)
constexpr int CAP = 163840;              // bucket capacity
constexpr int PBLK = 400;                // partition blocks
constexpr int PCHUNK = NE / PBLK;        // 4000 edges per partition block

// ---------------------------------------------------------------- P1: partition edges by col-range / row-range
__global__ __launch_bounds__(256) void k_part(const int* __restrict__ row,
                                              const int* __restrict__ col,
                                              int* __restrict__ colCnt,
                                              int* __restrict__ rowCnt,
                                              int* __restrict__ colbuf,
                                              unsigned short* __restrict__ rowbuf) {
  __shared__ int cntc[NR], cntr[NR];
  const int tid = threadIdx.x;
  const int e0 = blockIdx.x * PCHUNK;
  if (tid < NR) { cntc[tid] = 0; cntr[tid] = 0; }
  __syncthreads();
  for (int i = tid; i < PCHUNK; i += 256) {
    atomicAdd(&cntc[col[e0 + i] >> RSH], 1);
    atomicAdd(&cntr[row[e0 + i] >> RSH], 1);
  }
  __syncthreads();
  if (tid < NR) {
    cntc[tid] = atomicAdd(&colCnt[tid], cntc[tid]);
  } else if (tid >= 64 && tid < 64 + NR) {
    const int b = tid - 64;
    cntr[b] = atomicAdd(&rowCnt[b], cntr[b]);
  }
  __syncthreads();
  for (int i = tid; i < PCHUNK; i += 256) {
    const int r = row[e0 + i];
    const int c = col[e0 + i];
    const int bc = c >> RSH;
    const int pc = atomicAdd(&cntc[bc], 1);
    colbuf[(size_t)bc * CAP + pc] = (r << RSH) | (c & (RB - 1));
    const int br = r >> RSH;
    const int pr = atomicAdd(&cntr[br], 1);
    rowbuf[(size_t)br * CAP + pr] = (unsigned short)(r & (RB - 1));
  }
}

// ---------------------------------------------------------------- P2: per-(bucket,slice) LDS histogram
__global__ __launch_bounds__(1024) void k_hist2(const int* __restrict__ colbuf,
                                                const unsigned short* __restrict__ rowbuf,
                                                const int* __restrict__ colCnt,
                                                const int* __restrict__ rowCnt,
                                                int* __restrict__ PDc,
                                                int* __restrict__ PDd) {
  __shared__ int h[RB];
  const int tid = threadIdx.x;
  const int b = blockIdx.x, s = blockIdx.y, z = blockIdx.z;
  for (int i = tid; i < RB; i += 1024) h[i] = 0;
  __syncthreads();
  const int len = z ? rowCnt[b] : colCnt[b];
  const int sl = (len + SB - 1) / SB;
  const int st = s * sl;
  const int en = min(st + sl, len);
  if (z == 0) {
    const int* cb = colbuf + (size_t)b * CAP;
    for (int i = st + tid; i < en; i += 1024)
      atomicAdd(&h[cb[i] & (RB - 1)], 1);
  } else {
    const unsigned short* rb = rowbuf + (size_t)b * CAP;
    for (int i = st + tid; i < en; i += 1024)
      atomicAdd(&h[rb[i]], 1);
  }
  __syncthreads();
  int* pd = (z ? PDd : PDc) + ((size_t)b * SB + s) * RB;
  for (int i = tid; i < RB; i += 1024) pd[i] = h[i];
}

// ---------------------------------------------------------------- P3: per-node slice prefix + totals + dinv
__global__ __launch_bounds__(256) void k_csrmid2(const int* __restrict__ PDc,
                                                 const int* __restrict__ PDd,
                                                 int* __restrict__ Bpart,
                                                 int* __restrict__ cnt,
                                                 float* __restrict__ dinv) {
  const int n = blockIdx.x * 256 + threadIdx.x;
  if (n >= NN) return;
  const int b = n >> RSH, o = n & (RB - 1);
  int run = 0, dsum = 0;
#pragma unroll
  for (int s = 0; s < SB; s++) {
    Bpart[(size_t)s * NN + n] = run;
    run += PDc[((size_t)b * SB + s) * RB + o];
    dsum += PDd[((size_t)b * SB + s) * RB + o];
  }
  cnt[n] = run;
  dinv[n] = dsum > 0 ? rsqrtf((float)dsum) : 0.0f;
}

// ---------------------------------------------------------------- 3-phase exclusive scan of cnt
__global__ __launch_bounds__(256) void k_scan_a(const int* __restrict__ cnt,
                                                int* __restrict__ bsum) {
  __shared__ int sh[256];
  const int tid = threadIdx.x;
  const int i = blockIdx.x * 256 + tid;
  sh[tid] = (i < NN) ? cnt[i] : 0;
  __syncthreads();
  for (int st = 128; st > 0; st >>= 1) {
    if (tid < st) sh[tid] += sh[tid + st];
    __syncthreads();
  }
  if (tid == 0) bsum[blockIdx.x] = sh[0];
}

__global__ __launch_bounds__(512) void k_scan_b(const int* __restrict__ bsum,
                                                int* __restrict__ boff) {
  __shared__ int sh[512];
  const int tid = threadIdx.x;
  const int v = (tid < SC_NB) ? bsum[tid] : 0;
  sh[tid] = v;
  __syncthreads();
  for (int off = 1; off < 512; off <<= 1) {
    int t = (tid >= off) ? sh[tid - off] : 0;
    __syncthreads();
    sh[tid] += t;
    __syncthreads();
  }
  if (tid < SC_NB) boff[tid] = sh[tid] - v;  // exclusive
}

__global__ __launch_bounds__(256) void k_scan_c(const int* __restrict__ cnt,
                                                const int* __restrict__ boff,
                                                int* __restrict__ ptr) {
  __shared__ int sh[256];
  const int tid = threadIdx.x;
  const int i = blockIdx.x * 256 + tid;
  const int v = (i < NN) ? cnt[i] : 0;
  sh[tid] = v;
  __syncthreads();
  for (int off = 1; off < 256; off <<= 1) {
    int t = (tid >= off) ? sh[tid - off] : 0;
    __syncthreads();
    sh[tid] += t;
    __syncthreads();
  }
  const int excl = sh[tid] - v + boff[blockIdx.x];
  if (i < NN) {
    ptr[i] = excl;
    if (i == NN - 1) ptr[NN] = excl + v;
  }
}

// ---------------------------------------------------------------- P4: place edges via LDS cursors
__global__ __launch_bounds__(1024) void k_fill4(const int* __restrict__ colbuf,
                                                const int* __restrict__ colCnt,
                                                const int* __restrict__ ptr,
                                                const int* __restrict__ Bpart,
                                                int* __restrict__ eb) {
  __shared__ int cur[RB];
  const int tid = threadIdx.x;
  const int b = blockIdx.x, s = blockIdx.y;
  const int base = b << RSH;
  const int nmax = min(RB, NN - base);
  const int* bp = Bpart + (size_t)s * NN + base;
  for (int i = tid; i < nmax; i += 1024) cur[i] = ptr[base + i] + bp[i];
  __syncthreads();
  const int len = colCnt[b];
  const int sl = (len + SB - 1) / SB;
  const int st = s * sl;
  const int en = min(st + sl, len);
  const int* cb = colbuf + (size_t)b * CAP;
  for (int i = st + tid; i < en; i += 1024) {
    const int rec = cb[i];
    const int pos = atomicAdd(&cur[rec & (RB - 1)], 1);
    eb[pos] = rec >> RSH;
  }
}

// ---------------------------------------------------------------- prop: acc[n] = sum_{e: col=n} [dinv[s]*] p[src_e]
template <bool SCALE, bool ADD>
__global__ __launch_bounds__(256) void k_prop64(const float* __restrict__ p,
                                                const int* __restrict__ eb,
                                                const int* __restrict__ ptr,
                                                const float* __restrict__ g,
                                                const float* __restrict__ dinv,
                                                float* __restrict__ out) {
  const int node = blockIdx.x * 16 + (threadIdx.x >> 4);
  const int lane = threadIdx.x & 15;
  if (node >= NN) return;
  const int b = ptr[node], e = ptr[node + 1];
  float4 a0 = make_float4(0.f, 0.f, 0.f, 0.f);
  float4 a1 = make_float4(0.f, 0.f, 0.f, 0.f);
  float4 a2 = make_float4(0.f, 0.f, 0.f, 0.f);
  float4 a3 = make_float4(0.f, 0.f, 0.f, 0.f);
  const float4* hp = reinterpret_cast<const float4*>(p) + lane;
  int j = b;
  for (; j + 4 <= e; j += 4) {
    const int s0 = eb[j], s1 = eb[j + 1], s2 = eb[j + 2], s3 = eb[j + 3];
    const float w0 = SCALE ? dinv[s0] : 1.f;
    const float w1 = SCALE ? dinv[s1] : 1.f;
    const float w2 = SCALE ? dinv[s2] : 1.f;
    const float w3 = SCALE ? dinv[s3] : 1.f;
    const float4 h0 = hp[(size_t)s0 * 16];
    const float4 h1 = hp[(size_t)s1 * 16];
    const float4 h2 = hp[(size_t)s2 * 16];
    const float4 h3 = hp[(size_t)s3 * 16];
    if (SCALE) {
      a0.x += w0 * h0.x; a0.y += w0 * h0.y; a0.z += w0 * h0.z; a0.w += w0 * h0.w;
      a1.x += w1 * h1.x; a1.y += w1 * h1.y; a1.z += w1 * h1.z; a1.w += w1 * h1.w;
      a2.x += w2 * h2.x; a2.y += w2 * h2.y; a2.z += w2 * h2.z; a2.w += w2 * h2.w;
      a3.x += w3 * h3.x; a3.y += w3 * h3.y; a3.z += w3 * h3.z; a3.w += w3 * h3.w;
    } else {
      a0.x += h0.x; a0.y += h0.y; a0.z += h0.z; a0.w += h0.w;
      a1.x += h1.x; a1.y += h1.y; a1.z += h1.z; a1.w += h1.w;
      a2.x += h2.x; a2.y += h2.y; a2.z += h2.z; a2.w += h2.w;
      a3.x += h3.x; a3.y += h3.y; a3.z += h3.z; a3.w += h3.w;
    }
  }
  for (; j < e; j++) {
    const int s0 = eb[j];
    const float w0 = SCALE ? dinv[s0] : 1.f;
    const float4 h0 = hp[(size_t)s0 * 16];
    if (SCALE) {
      a0.x += w0 * h0.x; a0.y += w0 * h0.y; a0.z += w0 * h0.z; a0.w += w0 * h0.w;
    } else {
      a0.x += h0.x; a0.y += h0.y; a0.z += h0.z; a0.w += h0.w;
    }
  }
  a0.x += a1.x + a2.x + a3.x;
  a0.y += a1.y + a2.y + a3.y;
  a0.z += a1.z + a2.z + a3.z;
  a0.w += a1.w + a2.w + a3.w;
  if (ADD) {
    const float dn = dinv[node];
    const float4 gv = reinterpret_cast<const float4*>(g)[(size_t)node * 16 + lane];
    a0.x = gv.x - dn * a0.x;
    a0.y = gv.y - dn * a0.y;
    a0.z = gv.z - dn * a0.z;
    a0.w = gv.w - dn * a0.w;
  }
  reinterpret_cast<float4*>(out)[(size_t)node * 16 + lane] = a0;
}

// ---------------------------------------------------------------- layer-1 conv: h1 = x@W0 + (-dinv*y)@W1 + b
// Software-pipelined: two NAMED chunk buffers (A0/A1), loop steps 2 chunks -> all register
// indices static (no scratch). FMA runs see only W s_loads in the lgkm domain.
__global__ __launch_bounds__(512) void k_conv1(const float* __restrict__ x,
                                               const float* __restrict__ y,
                                               const float* __restrict__ dinv,
                                               const float* __restrict__ W,
                                               const float* __restrict__ bias,
                                               float* __restrict__ out) {
  constexpr int LDW = 68;
  __shared__ float XA[64][LDW];
  __shared__ float XY[64][LDW];
  const int tid = threadIdx.x;
  const int lane = tid & 63;
  const int wv = __builtin_amdgcn_readfirstlane(tid >> 6);  // 0..7
  const int n0 = blockIdx.x * 64;
  for (int idx = tid; idx < 1024; idx += 512) {
    const int n = idx >> 4, k4 = idx & 15;
    int node = n0 + n;
    if (node >= NN) node = NN - 1;
    const float4 av = *reinterpret_cast<const float4*>(x + (size_t)node * 64 + k4 * 4);
    float4 yv = *reinterpret_cast<const float4*>(y + (size_t)node * 64 + k4 * 4);
    const float dn = -dinv[node];
    yv.x *= dn; yv.y *= dn; yv.z *= dn; yv.w *= dn;
    *reinterpret_cast<float4*>(&XA[n][k4 * 4]) = av;
    *reinterpret_cast<float4*>(&XY[n][k4 * 4]) = yv;
  }
  __syncthreads();
  const int cw0 = wv * 16;
  const float* __restrict__ W0 = W + cw0;             // [64][128]
  const float* __restrict__ W1 = W + 64 * 128 + cw0;
  const float4* xrow = reinterpret_cast<const float4*>(&XA[lane][0]);
  const float4* yrow = reinterpret_cast<const float4*>(&XY[lane][0]);
  float acc[16];
#pragma unroll
  for (int j = 0; j < 16; j++) acc[j] = 0.f;

  auto compute8 = [&](const float4 (&a)[2], const float4 (&yy)[2], int kbase) {
#pragma unroll
    for (int q = 0; q < 2; q++) {
      const int k0 = kbase + q * 4;
#pragma unroll
      for (int j = 0; j < 16; j++)
        acc[j] += a[q].x * W0[(size_t)(k0 + 0) * 128 + j] + yy[q].x * W1[(size_t)(k0 + 0) * 128 + j];
#pragma unroll
      for (int j = 0; j < 16; j++)
        acc[j] += a[q].y * W0[(size_t)(k0 + 1) * 128 + j] + yy[q].y * W1[(size_t)(k0 + 1) * 128 + j];
#pragma unroll
      for (int j = 0; j < 16; j++)
        acc[j] += a[q].z * W0[(size_t)(k0 + 2) * 128 + j] + yy[q].z * W1[(size_t)(k0 + 2) * 128 + j];
#pragma unroll
      for (int j = 0; j < 16; j++)
        acc[j] += a[q].w * W0[(size_t)(k0 + 3) * 128 + j] + yy[q].w * W1[(size_t)(k0 + 3) * 128 + j];
    }
  };

  float4 A0[2], Y0[2], A1[2], Y1[2];
  A0[0] = xrow[0]; A0[1] = xrow[1];
  Y0[0] = yrow[0]; Y0[1] = yrow[1];
  for (int cc = 0; cc < 8; cc += 2) {                 // 8-k chunks
    A1[0] = xrow[(cc + 1) * 2 + 0]; A1[1] = xrow[(cc + 1) * 2 + 1];
    Y1[0] = yrow[(cc + 1) * 2 + 0]; Y1[1] = yrow[(cc + 1) * 2 + 1];
    compute8(A0, Y0, cc * 8);
    if (cc + 2 < 8) {
      A0[0] = xrow[(cc + 2) * 2 + 0]; A0[1] = xrow[(cc + 2) * 2 + 1];
      Y0[0] = yrow[(cc + 2) * 2 + 0]; Y0[1] = yrow[(cc + 2) * 2 + 1];
    }
    compute8(A1, Y1, (cc + 1) * 8);
  }

  const int node = n0 + lane;
  if (node < NN) {
#pragma unroll
    for (int j = 0; j < 16; j += 4) {
      float4 o = make_float4(acc[j] + bias[cw0 + j], acc[j + 1] + bias[cw0 + j + 1],
                             acc[j + 2] + bias[cw0 + j + 2], acc[j + 3] + bias[cw0 + j + 3]);
      *reinterpret_cast<float4*>(out + (size_t)node * 128 + cw0 + j) = o;
    }
  }
}

// ---------------------------------------------------------------- dual GEMM: g = bn(h)@Wa + b, p = dinv * (bn(h)@Wb)
// Same software-pipelined structure, 16-k chunks.
template <int Cin>
__global__ __launch_bounds__(512) void k_gemm_dual(const float* __restrict__ h,
                                                   const float* __restrict__ W,
                                                   const float* __restrict__ bias,
                                                   const float* __restrict__ scale,
                                                   const float* __restrict__ shift,
                                                   const float* __restrict__ dinv,
                                                   float* __restrict__ g,
                                                   float* __restrict__ p) {
  constexpr int LDW = Cin + 4;
  __shared__ float XA[64][LDW];
  const int tid = threadIdx.x;
  const int lane = tid & 63;
  const int wv = __builtin_amdgcn_readfirstlane(tid >> 6);  // 0..7
  const int n0 = blockIdx.x * 64;
  constexpr int C4 = Cin / 4;
  for (int idx = tid; idx < 64 * C4; idx += 512) {
    const int n = idx / C4, k4 = idx % C4;
    int node = n0 + n;
    if (node >= NN) node = NN - 1;
    float4 v = *reinterpret_cast<const float4*>(h + (size_t)node * Cin + k4 * 4);
    const float4 sc = *reinterpret_cast<const float4*>(scale + k4 * 4);
    const float4 sh = *reinterpret_cast<const float4*>(shift + k4 * 4);
    v.x = sc.x * v.x + sh.x; v.y = sc.y * v.y + sh.y;
    v.z = sc.z * v.z + sh.z; v.w = sc.w * v.w + sh.w;
    v.x = v.x >= 0.f ? v.x : LRELU_SLOPE * v.x;
    v.y = v.y >= 0.f ? v.y : LRELU_SLOPE * v.y;
    v.z = v.z >= 0.f ? v.z : LRELU_SLOPE * v.z;
    v.w = v.w >= 0.f ? v.w : LRELU_SLOPE * v.w;
    *reinterpret_cast<float4*>(&XA[n][k4 * 4]) = v;
  }
  __syncthreads();
  const int cw0 = wv * 8;
  const float* __restrict__ Wa = W + cw0;              // [Cin][64]
  const float* __restrict__ Wb = W + Cin * 64 + cw0;
  const float4* xrow = reinterpret_cast<const float4*>(&XA[lane][0]);
  float ag[8], ap[8];
#pragma unroll
  for (int j = 0; j < 8; j++) { ag[j] = 0.f; ap[j] = 0.f; }

  auto compute16 = [&](const float4 (&a)[4], int kbase) {
#pragma unroll
    for (int q = 0; q < 4; q++) {
      const int k0 = kbase + q * 4;
#pragma unroll
      for (int j = 0; j < 8; j++) {
        ag[j] += a[q].x * Wa[(size_t)(k0 + 0) * 64 + j];
        ap[j] += a[q].x * Wb[(size_t)(k0 + 0) * 64 + j];
      }
#pragma unroll
      for (int j = 0; j < 8; j++) {
        ag[j] += a[q].y * Wa[(size_t)(k0 + 1) * 64 + j];
        ap[j] += a[q].y * Wb[(size_t)(k0 + 1) * 64 + j];
      }
#pragma unroll
      for (int j = 0; j < 8; j++) {
        ag[j] += a[q].z * Wa[(size_t)(k0 + 2) * 64 + j];
        ap[j] += a[q].z * Wb[(size_t)(k0 + 2) * 64 + j];
      }
#pragma unroll
      for (int j = 0; j < 8; j++) {
        ag[j] += a[q].w * Wa[(size_t)(k0 + 3) * 64 + j];
        ap[j] += a[q].w * Wb[(size_t)(k0 + 3) * 64 + j];
      }
    }
  };

  constexpr int NCH = Cin / 16;                        // 4 or 8 (even)
  float4 A0[4], A1[4];
  A0[0] = xrow[0]; A0[1] = xrow[1]; A0[2] = xrow[2]; A0[3] = xrow[3];
  for (int cc = 0; cc < NCH; cc += 2) {
    A1[0] = xrow[(cc + 1) * 4 + 0]; A1[1] = xrow[(cc + 1) * 4 + 1];
    A1[2] = xrow[(cc + 1) * 4 + 2]; A1[3] = xrow[(cc + 1) * 4 + 3];
    compute16(A0, cc * 16);
    if (cc + 2 < NCH) {
      A0[0] = xrow[(cc + 2) * 4 + 0]; A0[1] = xrow[(cc + 2) * 4 + 1];
      A0[2] = xrow[(cc + 2) * 4 + 2]; A0[3] = xrow[(cc + 2) * 4 + 3];
    }
    compute16(A1, (cc + 1) * 16);
  }

  const int node = n0 + lane;
  if (node < NN) {
    const float dn = dinv[node];
#pragma unroll
    for (int j = 0; j < 8; j += 4) {
      float4 og = make_float4(ag[j] + bias[cw0 + j], ag[j + 1] + bias[cw0 + j + 1],
                              ag[j + 2] + bias[cw0 + j + 2], ag[j + 3] + bias[cw0 + j + 3]);
      *reinterpret_cast<float4*>(g + (size_t)node * 64 + cw0 + j) = og;
      float4 op = make_float4(ap[j] * dn, ap[j + 1] * dn, ap[j + 2] * dn, ap[j + 3] * dn);
      *reinterpret_cast<float4*>(p + (size_t)node * 64 + cw0 + j) = op;
    }
  }
}

// ---------------------------------------------------------------- BN stats (per-channel sum / sumsq)
template <int C>
__global__ __launch_bounds__(256) void k_bnstats(const float* __restrict__ h,
                                                 float* __restrict__ bnsum,
                                                 float* __restrict__ bnsq) {
  constexpr int RPB = 256 / C;
  constexpr int ROWS = 256;
  const int c = threadIdx.x % C;
  const int g = threadIdx.x / C;
  const int r0 = blockIdx.x * ROWS + g;
  const int rend = min(blockIdx.x * ROWS + ROWS, NN);
  float s = 0.f, sq = 0.f;
  for (int r = r0; r < rend; r += RPB) {
    float v = h[(size_t)r * C + c];
    s += v;
    sq += v * v;
  }
  __shared__ float ss[256], sg[256];
  ss[threadIdx.x] = s;
  sg[threadIdx.x] = sq;
  __syncthreads();
  for (int st = 128; st >= C; st >>= 1) {
    if (threadIdx.x < st) {
      ss[threadIdx.x] += ss[threadIdx.x + st];
      sg[threadIdx.x] += sg[threadIdx.x + st];
    }
    __syncthreads();
  }
  if (threadIdx.x < C) {
    atomicAdd(&bnsum[threadIdx.x], ss[threadIdx.x]);
    atomicAdd(&bnsq[threadIdx.x], sg[threadIdx.x]);
  }
}

template <int C>
__global__ void k_bnfin(const float* __restrict__ bnsum, const float* __restrict__ bnsq,
                        const float* __restrict__ gamma, const float* __restrict__ beta,
                        float* __restrict__ scale, float* __restrict__ shift) {
  int c = threadIdx.x;
  if (c < C) {
    float mean = bnsum[c] * (1.0f / NN);
    float var = bnsq[c] * (1.0f / NN) - mean * mean;
    float sc = gamma[c] * rsqrtf(var + BN_EPS);
    scale[c] = sc;
    shift[c] = beta[c] - mean * sc;
  }
}

// ----------------------------------------------------------------
extern "C" void kernel_launch(void* const* d_in, const int* in_sizes, int n_in,
                              void* d_out, int out_size, void* d_ws, size_t ws_size,
                              hipStream_t stream) {
  const float* x   = (const float*)d_in[0];
  const int*   ei  = (const int*)d_in[1];
  const int*   row = ei;
  const int*   col = ei + NE;
  const float* W1  = (const float*)d_in[2];
  const float* b1  = (const float*)d_in[3];
  const float* W2  = (const float*)d_in[4];
  const float* b2  = (const float*)d_in[5];
  const float* W3  = (const float*)d_in[6];
  const float* b3  = (const float*)d_in[7];
  const float* g1  = (const float*)d_in[8];
  const float* be1 = (const float*)d_in[9];
  const float* g2w = (const float*)d_in[10];
  const float* be2 = (const float*)d_in[11];
  float* out = (float*)d_out;

  char* ws = (char*)d_ws;
  size_t off = 0;
  auto alloc = [&](size_t bytes) -> void* {
    void* p = ws + off;
    off = (off + bytes + 255) & ~(size_t)255;
    return p;
  };

  // --- zeroed region (one tiny memset) ---
  float* bnsum1 = (float*)alloc(128 * 4);
  float* bnsq1  = (float*)alloc(128 * 4);
  float* bnsum2 = (float*)alloc(64 * 4);
  float* bnsq2  = (float*)alloc(64 * 4);
  int*   colCnt = (int*)alloc(NR * 4);
  int*   rowCnt = (int*)alloc(NR * 4);
  const size_t zero_bytes = off;
  // --- rest ---
  float* dinv   = (float*)alloc(NN * 4);
  int*   cnt    = (int*)alloc(NN * 4);
  int*   ptr    = (int*)alloc((NN + 1) * 4);
  int*   bsum   = (int*)alloc(SC_NB * 4);
  int*   boff   = (int*)alloc(SC_NB * 4);
  int*   eb     = (int*)alloc((size_t)NE * 4);
  float* scale1 = (float*)alloc(128 * 4);
  float* shift1 = (float*)alloc(128 * 4);
  float* scale2 = (float*)alloc(64 * 4);
  float* shift2 = (float*)alloc(64 * 4);
  float* bufA   = (float*)alloc((size_t)NN * 64 * 4);   // y1, later g2
  float* bufB   = (float*)alloc((size_t)NN * 128 * 4);  // colbuf|rowbuf, then h1, later g3|p3
  float* bufC   = (float*)alloc((size_t)NN * 64 * 4);   // PDc|PDd|Bpart, later p2
  float* bufD   = (float*)alloc((size_t)NN * 64 * 4);   // h2

  // build scratch aliases
  int* colbuf = (int*)bufB;                                   // [NR][CAP] 4B
  unsigned short* rowbuf = (unsigned short*)(colbuf + (size_t)NR * CAP);  // [NR][CAP] 2B
  int* PDc    = (int*)bufC;                                   // [NR][SB][RB]
  int* PDd    = PDc + (size_t)NR * SB * RB;                   // [NR][SB][RB]
  int* Bpart  = PDd + (size_t)NR * SB * RB;                   // [SB][NN]

  float* y1  = bufA;
  float* h1  = bufB;
  float* gg2 = bufA;
  float* p2  = bufC;
  float* h2  = bufD;
  float* gg3 = bufB;
  float* p3  = bufB + (size_t)NN * 64;

  hipMemsetAsync(d_ws, 0, zero_bytes, stream);

  // graph prep: two-level bucket counting sort (LDS atomics only on hot path)
  k_part<<<PBLK, 256, 0, stream>>>(row, col, colCnt, rowCnt, colbuf, rowbuf);
  k_hist2<<<dim3(NR, SB, 2), 1024, 0, stream>>>(colbuf, rowbuf, colCnt, rowCnt, PDc, PDd);
  k_csrmid2<<<(NN + 255) / 256, 256, 0, stream>>>(PDc, PDd, Bpart, cnt, dinv);
  k_scan_a<<<SC_NB, 256, 0, stream>>>(cnt, bsum);
  k_scan_b<<<1, 512, 0, stream>>>(bsum, boff);
  k_scan_c<<<SC_NB, 256, 0, stream>>>(cnt, boff, ptr);
  k_fill4<<<dim3(NR, SB), 1024, 0, stream>>>(colbuf, colCnt, ptr, Bpart, eb);

  const int gemmGrid = (NN + 63) / 64;
  const int propGrid = (NN * 16 + 255) / 256;

  // layer 1: y1 = sum dinv[s]*x[s] (scale fused); h1 = x@W1[0] + (-dinv*y1)@W1[1] + b1
  k_prop64<true, false><<<propGrid, 256, 0, stream>>>(x, eb, ptr, nullptr, dinv, y1);
  k_conv1<<<gemmGrid, 512, 0, stream>>>(x, y1, dinv, W1, b1, h1);
  k_bnstats<128><<<(NN + 255) / 256, 256, 0, stream>>>(h1, bnsum1, bnsq1);
  k_bnfin<128><<<1, 128, 0, stream>>>(bnsum1, bnsq1, g1, be1, scale1, shift1);

  // layer 2: g2 = bn(h1)@W2[0]+b2, p2 = dinv*(bn(h1)@W2[1]); h2 = g2 - dinv*sum_gather(p2)
  k_gemm_dual<128><<<gemmGrid, 512, 0, stream>>>(h1, W2, b2, scale1, shift1, dinv, gg2, p2);
  k_prop64<false, true><<<propGrid, 256, 0, stream>>>(p2, eb, ptr, gg2, dinv, h2);
  k_bnstats<64><<<(NN + 255) / 256, 256, 0, stream>>>(h2, bnsum2, bnsq2);
  k_bnfin<64><<<1, 64, 0, stream>>>(bnsum2, bnsq2, g2w, be2, scale2, shift2);

  // layer 3: g3 = bn(h2)@W3[0]+b3, p3 = dinv*(bn(h2)@W3[1]); out = g3 - dinv*sum_gather(p3)
  k_gemm_dual<64><<<gemmGrid, 512, 0, stream>>>(h2, W3, b3, scale2, shift2, dinv, gg3, p3);
  k_prop64<false, true><<<propGrid, 256, 0, stream>>>(p3, eb, ptr, gg3, dinv, out);
}